// Round 17
// baseline (319.899 us; speedup 1.0000x reference)
//
#include <hip/hip_runtime.h>

#define NN 100000
#define NE 1600000
#define HID 128
#define KEXT 160            // layer-1 K: 128 feat | 16 edge | deg | 1 | 14 zero
#define ROWB 320            // bytes per ext row (KEXT * 2)
#define BSH 9               // bucket shift: 512 nodes/bucket
#define BNODES 512
#define NB 196              // ceil(NN/512)
#define P2B 2048            // partition blocks (8 blocks/CU)
#define EPB2 782            // ceil(NE / P2B)
#define NROWP 100096        // padded row count for 128-row GEMM tiles
#define GGRID 782           // 782*128 = 100096
#define BN_EPS 1e-5f

typedef __attribute__((ext_vector_type(8))) short bf16x8;
typedef __attribute__((ext_vector_type(4))) float f32x4;
typedef unsigned long long u64;

__device__ inline unsigned short f2bf(float x) {
  union { float f; unsigned u; } v; v.f = x;
  unsigned r = v.u + 0x7FFFu + ((v.u >> 16) & 1u);
  return (unsigned short)(r >> 16);
}
__device__ inline unsigned pk2(float a, float b) {
  return (unsigned)f2bf(a) | ((unsigned)f2bf(b) << 16);
}
__device__ inline float bflo(unsigned p) { return __uint_as_float(p << 16); }
__device__ inline float bfhi(unsigned p) { return __uint_as_float(p & 0xffff0000u); }

__device__ inline void gload_lds16(const void* g, void* l) {
  __builtin_amdgcn_global_load_lds((const __attribute__((address_space(1))) void*)g,
                                   (__attribute__((address_space(3))) void*)l, 16, 0, 0);
}

// ---------------- fused: feat->bf16 | weights | ef->bf16 (eid order) | bucket counts ----------------
__global__ __launch_bounds__(256) void fbw_k(const float* __restrict__ f,
                                             unsigned* __restrict__ fb,
                                             const float* __restrict__ W1,
                                             const float* __restrict__ Wb,
                                             const float* __restrict__ bb,
                                             const float* __restrict__ b1,
                                             const float* __restrict__ W2,
                                             unsigned short* __restrict__ W1e,
                                             unsigned short* __restrict__ W2e,
                                             const float* __restrict__ ef,
                                             unsigned* __restrict__ efb16,
                                             const int* __restrict__ dst,
                                             int* __restrict__ cnts_s) {
  __shared__ int bh[NB];
  if (blockIdx.x < 25000) {
    int i = blockIdx.x * 256 + threadIdx.x;
    float2 v = ((const float2*)f)[i];
    fb[i] = pk2(v.x, v.y);
  } else if (blockIdx.x < 25080) {
    int idx = (blockIdx.x - 25000) * 256 + threadIdx.x;
    if (idx < 128 * KEXT) {
      int c = idx / KEXT, k = idx - c * KEXT;
      float v1 = 0.f;
      if (k < 128) v1 = W1[c * HID + k];
      else if (k < 144) v1 = Wb[c * 16 + (k - 128)];
      else if (k == 144) v1 = bb[c];
      else if (k == 145) v1 = b1[c];
      W1e[idx] = f2bf(v1);
    }
    if (idx < 128 * 128) W2e[idx] = f2bf(W2[(idx >> 7) * HID + (idx & 127)]);
  } else if (blockIdx.x < 31330) {
    int e = (blockIdx.x - 25080) * 256 + threadIdx.x;   // 6250*256 = NE exact
    const float4* efp = (const float4*)(ef + (size_t)e * 16);
    float4 a = efp[0], b4 = efp[1], c4 = efp[2], d4 = efp[3];
    uint4 w0, w1;
    w0.x = pk2(a.x, a.y);   w0.y = pk2(a.z, a.w);
    w0.z = pk2(b4.x, b4.y); w0.w = pk2(b4.z, b4.w);
    w1.x = pk2(c4.x, c4.y); w1.y = pk2(c4.z, c4.w);
    w1.z = pk2(d4.x, d4.y); w1.w = pk2(d4.z, d4.w);
    uint4* op = (uint4*)(efb16 + (size_t)e * 8);
    op[0] = w0;
    op[1] = w1;
  } else {
    int blk = blockIdx.x - 31330;          // 0..P2B-1
    int b0 = blk * EPB2, e1 = min(b0 + EPB2, NE);
    for (int i = threadIdx.x; i < NB; i += 256) bh[i] = 0;
    __syncthreads();
    for (int e = b0 + threadIdx.x; e < e1; e += 256) atomicAdd(&bh[dst[e] >> BSH], 1);
    __syncthreads();
    for (int i = threadIdx.x; i < NB; i += 256) cnts_s[i * P2B + blk] = bh[i];
  }
}

// ---------------- per-bucket scans over 2048 blocks (Q=8 padded + real) ----------------
__global__ __launch_bounds__(1024) void cscan_k(int* __restrict__ cnts_s,
                                                int* __restrict__ bcnt_s,
                                                int* __restrict__ bcnt_r) {
  __shared__ int s[1024];
  int b = blockIdx.x, t = threadIdx.x;
  int x0 = cnts_s[b * P2B + 2 * t];
  int x1 = cnts_s[b * P2B + 2 * t + 1];
  int xs0 = (x0 + 7) & ~7;
  int xs1 = (x1 + 7) & ~7;
  s[t] = xs0 + xs1; __syncthreads();
  for (int off = 1; off < 1024; off <<= 1) {
    int v = (t >= off) ? s[t - off] : 0; __syncthreads();
    s[t] += v; __syncthreads();
  }
  int exclp = s[t] - (xs0 + xs1);
  cnts_s[b * P2B + 2 * t] = exclp;
  cnts_s[b * P2B + 2 * t + 1] = exclp + xs0;
  if (t == 1023) bcnt_s[b] = s[1023];
  __syncthreads();
  s[t] = x0 + x1; __syncthreads();
  for (int off = 1; off < 1024; off <<= 1) {
    int v = (t >= off) ? s[t - off] : 0; __syncthreads();
    s[t] += v; __syncthreads();
  }
  if (t == 1023) bcnt_r[b] = s[1023];
}

// ---------------- bucket-level scans ----------------
__global__ __launch_bounds__(256) void bscan_k(const int* __restrict__ bcnt_r,
                                               const int* __restrict__ bcnt_s,
                                               int* __restrict__ bbase_r,
                                               int* __restrict__ bbase_s,
                                               int* __restrict__ rs) {
  __shared__ int s[256];
  int t = threadIdx.x;
#pragma unroll
  for (int pass = 0; pass < 2; ++pass) {
    const int* in = (pass == 0) ? bcnt_r : bcnt_s;
    int* out = (pass == 0) ? bbase_r : bbase_s;
    int x = (t < NB) ? in[t] : 0;
    s[t] = x; __syncthreads();
    for (int off = 1; off < 256; off <<= 1) {
      int v = (t >= off) ? s[t - off] : 0; __syncthreads();
      s[t] += v; __syncthreads();
    }
    if (t < NB) out[t] = s[t] - x;
    if (t == NB - 1) out[NB] = s[t];
    __syncthreads();
  }
  if (t == 0) rs[NN] = NE;
}

// ---------------- partition: u64 stg only {src|d9|valid|eid}, Q=8 chunks ----------------
__global__ __launch_bounds__(256) void part3_k(const int* __restrict__ src,
                                               const int* __restrict__ dst,
                                               const int* __restrict__ bbase_s,
                                               const int* __restrict__ cnts_s,
                                               u64* __restrict__ stg) {
  __shared__ int th[NB], ts[NB], cnt2[NB], st_s[NB];
  __shared__ int sscan[256];
  __shared__ unsigned spk[EPB2 + 1];
  int blk = blockIdx.x, tid = threadIdx.x;
  int b0 = blk * EPB2;
  int tc = min(EPB2, NE - b0);
  if (tc < 0) tc = 0;
  for (int i = tid; i < NB; i += 256) {
    th[i] = 0; cnt2[i] = 0;
    st_s[i] = bbase_s[i] + cnts_s[i * P2B + blk];
  }
  __syncthreads();
  for (int le = tid; le < tc; le += 256) atomicAdd(&th[dst[b0 + le] >> BSH], 1);
  __syncthreads();
  sscan[tid] = (tid < NB) ? th[tid] : 0;
  __syncthreads();
  for (int off = 1; off < 256; off <<= 1) {
    int v = (tid >= off) ? sscan[tid - off] : 0;
    __syncthreads();
    sscan[tid] += v;
    __syncthreads();
  }
  if (tid < NB) ts[tid] = sscan[tid] - th[tid];
  __syncthreads();
  for (int le = tid; le < tc; le += 256) {
    int d = dst[b0 + le];
    int b = d >> BSH;
    int slot = ts[b] + atomicAdd(&cnt2[b], 1);
    spk[slot] = ((unsigned)b << 20) | ((unsigned)(d & (BNODES - 1)) << 11) | (unsigned)le;
  }
  __syncthreads();
  for (int s2 = tid; s2 < tc; s2 += 256) {
    unsigned pk = spk[s2];
    int b = pk >> 20, d9 = (pk >> 11) & 511, le = pk & 2047;
    int e = b0 + le;
    int gs = st_s[b] + (s2 - ts[b]);
    stg[gs] = (u64)(unsigned)src[e] | ((u64)(unsigned)d9 << 17) | (1ULL << 26) |
              ((u64)(unsigned)e << 27);
  }
  __syncthreads();
  for (int i = tid; i < NB; i += 256) {
    int c = th[i];
    int cs = (c + 7) & ~7;
    for (int j = c; j < cs; ++j) stg[st_s[i] + j] = 0ULL;
  }
}

// ---------------- node sort: writes rs, fin(src), eidS(eid) directly ----------------
__global__ __launch_bounds__(512) void bsort_k(const u64* __restrict__ stg,
                                               const int* __restrict__ bbase_s,
                                               const int* __restrict__ bbase_r,
                                               int* __restrict__ rs,
                                               unsigned* __restrict__ fin,
                                               unsigned* __restrict__ eidS) {
  __shared__ int h[BNODES], sc[BNODES], cur[BNODES];
  int b = blockIdx.x, n0 = b << BSH, tid = threadIdx.x;
  int s0p = bbase_s[b], e1p = bbase_s[b + 1];
  int s0r = bbase_r[b];
  h[tid] = 0;
  __syncthreads();
  for (int i = s0p + tid; i < e1p; i += 512) {
    u64 rec = stg[i];
    if ((rec >> 26) & 1) atomicAdd(&h[(int)(rec >> 17) & (BNODES - 1)], 1);
  }
  __syncthreads();
  sc[tid] = h[tid];
  __syncthreads();
  for (int off = 1; off < BNODES; off <<= 1) {
    int v = (tid >= off) ? sc[tid - off] : 0;
    __syncthreads();
    sc[tid] += v;
    __syncthreads();
  }
  int excl = sc[tid] - h[tid];
  cur[tid] = s0r + excl;
  int n = n0 + tid;
  if (n < NN) rs[n] = s0r + excl;
  __syncthreads();
  for (int i = s0p + tid; i < e1p; i += 512) {
    u64 rec = stg[i];
    if ((rec >> 26) & 1) {
      int d = (int)(rec >> 17) & (BNODES - 1);
      int p = atomicAdd(&cur[d], 1);
      fin[p] = (unsigned)(rec & 0x1FFFF);
      eidS[p] = (unsigned)((rec >> 27) & 0x1FFFFF);
    }
  }
}

// ---------------- per-node ef sum: 8 lanes/node, random 32B efb16 reads ----------------
__global__ __launch_bounds__(256) void efsum_k(const int* __restrict__ rs,
                                               const unsigned* __restrict__ eidS,
                                               const unsigned* __restrict__ efb16,
                                               unsigned* __restrict__ efsum) {
  int g = threadIdx.x >> 3;       // node sub-index 0..31
  int k = threadIdx.x & 7;
  int n = blockIdx.x * 32 + g;    // 3125*32 = 100000 exact
  int j0 = rs[n], j1 = rs[n + 1];
  float a0 = 0.f, a1 = 0.f;
  for (int j = j0; j < j1; ++j) {
    int eid = (int)eidS[j];
    unsigned u = efb16[(size_t)eid * 8 + k];
    a0 += bflo(u); a1 += bfhi(u);
  }
  efsum[(size_t)n * 8 + k] = pk2(a0, a1);
}

// ---------------- gather: feat mailbox (8-wide ILP, XCD swizzle) ----------------
__global__ __launch_bounds__(256) void feg_k(const unsigned* __restrict__ fb,
                                             const int* __restrict__ rs,
                                             const unsigned* __restrict__ fin,
                                             const unsigned* __restrict__ efsum,
                                             unsigned short* __restrict__ A1) {
  int bid = (int)(blockIdx.x & 7) * 3125 + (int)(blockIdx.x >> 3);
  int wid = threadIdx.x >> 6, lane = threadIdx.x & 63;
  int node = bid * 4 + wid;
  if (node >= NN) return;
  int start = rs[node], end = rs[node + 1];
  float ax0 = 0.f, ay0 = 0.f, ax1 = 0.f, ay1 = 0.f;
  float ax2 = 0.f, ay2 = 0.f, ax3 = 0.f, ay3 = 0.f;
  float ax4 = 0.f, ay4 = 0.f, ax5 = 0.f, ay5 = 0.f;
  float ax6 = 0.f, ay6 = 0.f, ax7 = 0.f, ay7 = 0.f;
  int i = start;
  for (; i + 8 <= end; i += 8) {
    int sl = 0;
    if (lane < 8) sl = (int)fin[i + lane];
    int s0 = __shfl(sl, 0), s1 = __shfl(sl, 1), s2 = __shfl(sl, 2), s3 = __shfl(sl, 3);
    int s4 = __shfl(sl, 4), s5 = __shfl(sl, 5), s6 = __shfl(sl, 6), s7 = __shfl(sl, 7);
    unsigned p0 = fb[s0 * 64 + lane];
    unsigned p1 = fb[s1 * 64 + lane];
    unsigned p2 = fb[s2 * 64 + lane];
    unsigned p3 = fb[s3 * 64 + lane];
    unsigned p4 = fb[s4 * 64 + lane];
    unsigned p5 = fb[s5 * 64 + lane];
    unsigned p6 = fb[s6 * 64 + lane];
    unsigned p7 = fb[s7 * 64 + lane];
    ax0 += bflo(p0); ay0 += bfhi(p0);
    ax1 += bflo(p1); ay1 += bfhi(p1);
    ax2 += bflo(p2); ay2 += bfhi(p2);
    ax3 += bflo(p3); ay3 += bfhi(p3);
    ax4 += bflo(p4); ay4 += bfhi(p4);
    ax5 += bflo(p5); ay5 += bfhi(p5);
    ax6 += bflo(p6); ay6 += bfhi(p6);
    ax7 += bflo(p7); ay7 += bfhi(p7);
  }
  for (; i < end; ++i) {
    int sl = 0;
    if (lane == 0) sl = (int)fin[i];
    int s0 = __shfl(sl, 0);
    unsigned p0 = fb[s0 * 64 + lane];
    ax0 += bflo(p0); ay0 += bfhi(p0);
  }
  float ax = ((ax0 + ax1) + (ax2 + ax3)) + ((ax4 + ax5) + (ax6 + ax7));
  float ay = ((ay0 + ay1) + (ay2 + ay3)) + ((ay4 + ay5) + (ay6 + ay7));
  char* rowp = (char*)A1 + (size_t)node * ROWB;
  *(unsigned*)(rowp + lane * 4) = pk2(ax, ay);
  if (lane < 8) {
    *(unsigned*)(rowp + 256 + 4 * lane) = efsum[(size_t)node * 8 + lane];
  } else if (lane < 16) {
    int j2 = lane - 8;
    *(unsigned*)(rowp + 288 + 4 * j2) =
        (j2 == 0) ? pk2((float)(end - start), 1.0f) : 0u;
  }
}

// ---------------- GEMM 1: 128-row tile, K=160, stats -> privatized ----------------
__global__ __launch_bounds__(256) void gemm1_k(
    const unsigned short* __restrict__ A, const unsigned short* __restrict__ W,
    unsigned short* __restrict__ outb, float* __restrict__ statsP) {
  __shared__ __align__(16) char sA[128 * ROWB];
  __shared__ __align__(16) char sW[128 * ROWB];
  const int tid = threadIdx.x;
  const int wid = tid >> 6, lane = tid & 63;
  const size_t r0 = (size_t)blockIdx.x * 128;

#pragma unroll
  for (int q = 0; q < 10; ++q) {
    int s = q * 256 + tid;
    int row = (s * 3277) >> 16;
    int c = s - row * 20;
    int csrc = (c < 16) ? (c ^ (row & 7)) : (16 + ((c - 16) ^ (row & 3)));
    gload_lds16((const char*)A + (r0 + row) * ROWB + csrc * 16,
                sA + (size_t)(q * 256 + wid * 64) * 16);
  }
#pragma unroll
  for (int q = 0; q < 10; ++q) {
    int s = q * 256 + tid;
    int row = (s * 3277) >> 16;
    int c = s - row * 20;
    int csrc = (c < 16) ? (c ^ (row & 7)) : (16 + ((c - 16) ^ (row & 3)));
    gload_lds16((const char*)W + (size_t)row * ROWB + csrc * 16,
                sW + (size_t)(q * 256 + wid * 64) * 16);
  }
  __syncthreads();

  const int l15 = lane & 15;
  const int kgr = lane >> 4;
  bf16x8 afrag[2][5];
#pragma unroll
  for (int rt = 0; rt < 2; ++rt) {
    int arow = wid * 32 + rt * 16 + l15;
#pragma unroll
    for (int ks = 0; ks < 5; ++ks) {
      int creq = ks * 4 + kgr;
      int csw = (creq < 16) ? (creq ^ (arow & 7)) : (16 + ((creq - 16) ^ (arow & 3)));
      afrag[rt][ks] = *(const bf16x8*)(sA + arow * ROWB + csw * 16);
    }
  }
  f32x4 acc[2][8];
#pragma unroll
  for (int rt = 0; rt < 2; ++rt)
#pragma unroll
    for (int ct = 0; ct < 8; ++ct) acc[rt][ct] = (f32x4){0.f, 0.f, 0.f, 0.f};
#pragma unroll
  for (int ct = 0; ct < 8; ++ct) {
    int brow = ct * 16 + l15;
#pragma unroll
    for (int ks = 0; ks < 5; ++ks) {
      int creq = ks * 4 + kgr;
      int csw = (creq < 16) ? (creq ^ (brow & 7)) : (16 + ((creq - 16) ^ (brow & 3)));
      bf16x8 bfrag = *(const bf16x8*)(sW + brow * ROWB + csw * 16);
      acc[0][ct] = __builtin_amdgcn_mfma_f32_16x16x32_bf16(afrag[0][ks], bfrag, acc[0][ct], 0, 0, 0);
      acc[1][ct] = __builtin_amdgcn_mfma_f32_16x16x32_bf16(afrag[1][ks], bfrag, acc[1][ct], 0, 0, 0);
    }
  }

  float cs[8], cq[8];
#pragma unroll
  for (int ct = 0; ct < 8; ++ct) { cs[ct] = 0.f; cq[ct] = 0.f; }
#pragma unroll
  for (int rt = 0; rt < 2; ++rt) {
    const size_t orow0 = r0 + wid * 32 + rt * 16 + kgr * 4;
#pragma unroll
    for (int ct = 0; ct < 8; ++ct) {
      int col = ct * 16 + l15;
#pragma unroll
      for (int r = 0; r < 4; ++r) {
        size_t row = orow0 + r;
        if (row < NN) {
          float v = acc[rt][ct][r];
          outb[row * HID + col] = f2bf(v);
          cs[ct] += v; cq[ct] += v * v;
        }
      }
    }
  }
#pragma unroll
  for (int ct = 0; ct < 8; ++ct) {
    cs[ct] += __shfl_xor(cs[ct], 16); cs[ct] += __shfl_xor(cs[ct], 32);
    cq[ct] += __shfl_xor(cq[ct], 16); cq[ct] += __shfl_xor(cq[ct], 32);
  }
  __syncthreads();
  float* red = (float*)sA;
  if (lane < 16) {
#pragma unroll
    for (int ct = 0; ct < 8; ++ct) {
      red[wid * 256 + ct * 16 + l15] = cs[ct];
      red[wid * 256 + 128 + ct * 16 + l15] = cq[ct];
    }
  }
  __syncthreads();
  if (tid < 256) {
    float* base = statsP + (size_t)(blockIdx.x & 15) * 512;
    float s_ = red[tid] + red[256 + tid] + red[512 + tid] + red[768 + tid];
    atomicAdd(&base[tid], s_);
  }
}

// ---------------- stats reduce ----------------
__global__ void bnred_k(const float* __restrict__ statsP, int base,
                        const float* __restrict__ gamma, const float* __restrict__ beta,
                        float* __restrict__ scale, float* __restrict__ shift) {
  int c = threadIdx.x;
  if (c < 128) {
    float s_ = 0.f, q_ = 0.f;
#pragma unroll
    for (int i = 0; i < 16; ++i) {
      s_ += statsP[i * 512 + base + c];
      q_ += statsP[i * 512 + base + 128 + c];
    }
    const float invN = 1.f / (float)NN;
    float m = s_ * invN;
    float var = q_ * invN - m * m;
    float inv = rsqrtf(var + BN_EPS);
    float sc = gamma[c] * inv;
    scale[c] = sc;
    shift[c] = beta[c] - m * sc;
  }
}

// ---------------- GEMM 2: fused BN1+ReLU A-stage, bf16 residual, in-place ----------------
__global__ __launch_bounds__(256) void gemm2_k(
    const unsigned* __restrict__ t, const unsigned short* __restrict__ W,
    const float* __restrict__ scale, const float* __restrict__ shift,
    const float* __restrict__ b2, const unsigned* __restrict__ fbres,
    unsigned short* __restrict__ outb, float* __restrict__ statsP) {
  __shared__ __align__(16) char sA[128 * 256];
  __shared__ __align__(16) char sW[128 * 256];
  __shared__ float ssc[128], ssh[128];
  const int tid = threadIdx.x;
  const int wid = tid >> 6, lane = tid & 63;
  const size_t r0 = (size_t)blockIdx.x * 128;

  if (tid < 128) {
    ssc[tid] = scale[tid];
    ssh[tid] = shift[tid];
  }
#pragma unroll
  for (int q = 0; q < 8; ++q) {
    int s = q * 256 + tid;
    int row = s >> 4, c = s & 15;
    int csrc = c ^ (row & 7);
    gload_lds16((const char*)W + (size_t)row * 256 + csrc * 16,
                sW + (size_t)(q * 256 + wid * 64) * 16);
  }
  __syncthreads();

#pragma unroll
  for (int q = 0; q < 8; ++q) {
    int s = q * 256 + tid;
    int sr = s >> 4, c = s & 15;
    size_t grow = r0 + sr;
    uint4 v = make_uint4(0, 0, 0, 0);
    if (grow < NN) v = *(const uint4*)(t + grow * 64 + c * 4);
    int k = c * 8;
    unsigned o0 = pk2(fmaxf(0.f, fmaf(bflo(v.x), ssc[k + 0], ssh[k + 0])),
                      fmaxf(0.f, fmaf(bfhi(v.x), ssc[k + 1], ssh[k + 1])));
    unsigned o1 = pk2(fmaxf(0.f, fmaf(bflo(v.y), ssc[k + 2], ssh[k + 2])),
                      fmaxf(0.f, fmaf(bfhi(v.y), ssc[k + 3], ssh[k + 3])));
    unsigned o2 = pk2(fmaxf(0.f, fmaf(bflo(v.z), ssc[k + 4], ssh[k + 4])),
                      fmaxf(0.f, fmaf(bfhi(v.z), ssc[k + 5], ssh[k + 5])));
    unsigned o3 = pk2(fmaxf(0.f, fmaf(bflo(v.w), ssc[k + 6], ssh[k + 6])),
                      fmaxf(0.f, fmaf(bfhi(v.w), ssc[k + 7], ssh[k + 7])));
    int csw = c ^ (sr & 7);
    uint4 w4; w4.x = o0; w4.y = o1; w4.z = o2; w4.w = o3;
    *(uint4*)(sA + sr * 256 + csw * 16) = w4;
  }
  __syncthreads();

  const int l15 = lane & 15;
  const int kgr = lane >> 4;
  bf16x8 afrag[2][4];
#pragma unroll
  for (int rt = 0; rt < 2; ++rt) {
    int arow = wid * 32 + rt * 16 + l15;
#pragma unroll
    for (int ks = 0; ks < 4; ++ks) {
      int creq = ks * 4 + kgr;
      int csw = creq ^ (arow & 7);
      afrag[rt][ks] = *(const bf16x8*)(sA + arow * 256 + csw * 16);
    }
  }
  f32x4 acc[2][8];
#pragma unroll
  for (int rt = 0; rt < 2; ++rt)
#pragma unroll
    for (int ct = 0; ct < 8; ++ct) acc[rt][ct] = (f32x4){0.f, 0.f, 0.f, 0.f};
#pragma unroll
  for (int ct = 0; ct < 8; ++ct) {
    int brow = ct * 16 + l15;
#pragma unroll
    for (int ks = 0; ks < 4; ++ks) {
      int creq = ks * 4 + kgr;
      int csw = creq ^ (brow & 7);
      bf16x8 bfrag = *(const bf16x8*)(sW + brow * 256 + csw * 16);
      acc[0][ct] = __builtin_amdgcn_mfma_f32_16x16x32_bf16(afrag[0][ks], bfrag, acc[0][ct], 0, 0, 0);
      acc[1][ct] = __builtin_amdgcn_mfma_f32_16x16x32_bf16(afrag[1][ks], bfrag, acc[1][ct], 0, 0, 0);
    }
  }

  float cs[8], cq[8];
#pragma unroll
  for (int ct = 0; ct < 8; ++ct) { cs[ct] = 0.f; cq[ct] = 0.f; }
#pragma unroll
  for (int rt = 0; rt < 2; ++rt) {
    const size_t orow0 = r0 + wid * 32 + rt * 16 + kgr * 4;
#pragma unroll
    for (int ct = 0; ct < 8; ++ct) {
      int col = ct * 16 + l15;
      float b2v = b2[col];
      int ci = col >> 1, par = col & 1;
#pragma unroll
      for (int r = 0; r < 4; ++r) {
        size_t row = orow0 + r;
        if (row < NN) {
          unsigned u = fbres[row * 64 + ci];
          float resid = par ? bfhi(u) : bflo(u);
          float v = acc[rt][ct][r] + b2v + resid;
          outb[row * HID + col] = f2bf(v);
          cs[ct] += v; cq[ct] += v * v;
        }
      }
    }
  }
#pragma unroll
  for (int ct = 0; ct < 8; ++ct) {
    cs[ct] += __shfl_xor(cs[ct], 16); cs[ct] += __shfl_xor(cs[ct], 32);
    cq[ct] += __shfl_xor(cq[ct], 16); cq[ct] += __shfl_xor(cq[ct], 32);
  }
  __syncthreads();
  float* red = (float*)sA;
  if (lane < 16) {
#pragma unroll
    for (int ct = 0; ct < 8; ++ct) {
      red[wid * 256 + ct * 16 + l15] = cs[ct];
      red[wid * 256 + 128 + ct * 16 + l15] = cq[ct];
    }
  }
  __syncthreads();
  if (tid < 256) {
    float* base = statsP + (size_t)(blockIdx.x & 15) * 512 + 256;
    float s_ = red[tid] + red[256 + tid] + red[512 + tid] + red[768 + tid];
    atomicAdd(&base[tid], s_);
  }
}

// ---------------- final BN+ReLU -> f32 out ----------------
__global__ __launch_bounds__(256) void bn_final_k(const unsigned* __restrict__ t,
                                                  const float* __restrict__ scale,
                                                  const float* __restrict__ shift,
                                                  float* __restrict__ o) {
  __shared__ float ssc[128], ssh[128];
  int tid = threadIdx.x;
  if (tid < 128) { ssc[tid] = scale[tid]; ssh[tid] = shift[tid]; }
  __syncthreads();
  int i = blockIdx.x * 256 + tid;
  if (i >= NN * 64) return;
  unsigned p = t[i];
  int c = (i & 63) * 2;
  float2 v;
  v.x = fmaxf(0.f, fmaf(bflo(p), ssc[c], ssh[c]));
  v.y = fmaxf(0.f, fmaf(bfhi(p), ssc[c + 1], ssh[c + 1]));
  ((float2*)o)[i] = v;
}

extern "C" void kernel_launch(void* const* d_in, const int* in_sizes, int n_in,
                              void* d_out, int out_size, void* d_ws, size_t ws_size,
                              hipStream_t stream) {
  (void)in_sizes; (void)n_in; (void)out_size; (void)ws_size;
  const float* features   = (const float*)d_in[0];
  const float* edge_feats = (const float*)d_in[1];
  const int*   src        = (const int*)d_in[2];
  const int*   dst        = (const int*)d_in[3];
  const float* Wb         = (const float*)d_in[4];
  const float* bb         = (const float*)d_in[5];
  const float* W1         = (const float*)d_in[6];
  const float* b1         = (const float*)d_in[7];
  const float* W2         = (const float*)d_in[8];
  const float* b2         = (const float*)d_in[9];
  const float* gamma1     = (const float*)d_in[10];
  const float* beta1      = (const float*)d_in[11];
  const float* gamma2     = (const float*)d_in[12];
  const float* beta2      = (const float*)d_in[13];
  float* outp = (float*)d_out;

  char* wsb = (char*)d_ws;
  size_t off = 0;
  auto alloc = [&](size_t nbytes) -> void* {
    off = (off + 255) & ~(size_t)255;
    void* p = wsb + off;
    off += nbytes;
    return p;
  };
  const size_t STGN = (size_t)NE + 7 * (size_t)NB * P2B + 64;   // Q=8 padding
  int* row_start = (int*)alloc((size_t)(NN + 1) * 4);
  int* bcnt_r    = (int*)alloc(NB * 4);
  int* bcnt_s    = (int*)alloc(NB * 4);
  int* bbase_r   = (int*)alloc((NB + 1) * 4);
  int* bbase_s   = (int*)alloc((NB + 1) * 4);
  int* cnts_s    = (int*)alloc((size_t)NB * P2B * 4);
  float* statsP  = (float*)alloc(16 * 512 * 4);
  float* scsh    = (float*)alloc(512 * 4);
  unsigned* featb = (unsigned*)alloc((size_t)NN * 64 * 4);          // fb, stays live
  unsigned short* tbuf = (unsigned short*)alloc((size_t)NROWP * HID * 2);
  unsigned short* A1e = (unsigned short*)alloc((size_t)NROWP * ROWB);
  unsigned short* W1e = (unsigned short*)alloc(128 * KEXT * 2);
  unsigned short* W2e = (unsigned short*)alloc(128 * 128 * 2);
  u64* stg       = (u64*)alloc(STGN * 8);
  unsigned* fin  = (unsigned*)alloc((size_t)NE * 4);
  unsigned* eidS = (unsigned*)alloc((size_t)NE * 4);
  unsigned* efb16 = (unsigned*)alloc((size_t)NE * 32);
  unsigned* efsum = (unsigned*)alloc((size_t)NN * 32);

  hipMemsetAsync(statsP, 0, 16 * 512 * 4, stream);
  hipMemsetAsync((char*)A1e + (size_t)NN * ROWB, 0, (NROWP - NN) * ROWB, stream);

  fbw_k<<<31330 + P2B, 256, 0, stream>>>(features, featb, W1, Wb, bb, b1, W2,
                                         W1e, W2e, edge_feats, efb16, dst, cnts_s);
  cscan_k<<<NB, 1024, 0, stream>>>(cnts_s, bcnt_s, bcnt_r);
  bscan_k<<<1, 256, 0, stream>>>(bcnt_r, bcnt_s, bbase_r, bbase_s, row_start);
  part3_k<<<P2B, 256, 0, stream>>>(src, dst, bbase_s, cnts_s, stg);
  bsort_k<<<NB, 512, 0, stream>>>(stg, bbase_s, bbase_r, row_start, fin, eidS);
  efsum_k<<<3125, 256, 0, stream>>>(row_start, eidS, efb16, efsum);
  feg_k<<<25000, 256, 0, stream>>>(featb, row_start, fin, efsum, A1e);

  gemm1_k<<<GGRID, 256, 0, stream>>>(A1e, W1e, tbuf, statsP);
  bnred_k<<<1, 128, 0, stream>>>(statsP, 0, gamma1, beta1, scsh, scsh + 128);
  gemm2_k<<<GGRID, 256, 0, stream>>>((const unsigned*)tbuf, W2e, scsh, scsh + 128,
                                     b2, featb, tbuf, statsP);
  bnred_k<<<1, 128, 0, stream>>>(statsP, 256, gamma2, beta2, scsh + 256, scsh + 384);
  bn_final_k<<<25000, 256, 0, stream>>>((const unsigned*)tbuf, scsh + 256, scsh + 384,
                                        outp);
}

// Round 18
// 291.014 us; speedup vs baseline: 1.0993x; 1.0993x over previous
//
#include <hip/hip_runtime.h>

#define NN 100000
#define NE 1600000
#define HID 128
#define KEXT 160            // layer-1 K: 128 feat | 16 edge | deg | 1 | 14 zero
#define ROWB 320            // bytes per ext row (KEXT * 2)
#define BSH 9               // bucket shift: 512 nodes/bucket
#define BNODES 512
#define NB 196              // ceil(NN/512)
#define P2B 2048            // partition blocks (8 blocks/CU)
#define EPB2 782            // ceil(NE / P2B)
#define SCAP 10240          // bsort pool entries (40 KB)
#define NROWP 100096        // padded row count for 128-row GEMM tiles
#define GGRID 782           // 782*128 = 100096
#define BN_EPS 1e-5f

typedef __attribute__((ext_vector_type(8))) short bf16x8;
typedef __attribute__((ext_vector_type(4))) float f32x4;

__device__ inline unsigned short f2bf(float x) {
  union { float f; unsigned u; } v; v.f = x;
  unsigned r = v.u + 0x7FFFu + ((v.u >> 16) & 1u);
  return (unsigned short)(r >> 16);
}
__device__ inline unsigned pk2(float a, float b) {
  return (unsigned)f2bf(a) | ((unsigned)f2bf(b) << 16);
}
__device__ inline float bflo(unsigned p) { return __uint_as_float(p << 16); }
__device__ inline float bfhi(unsigned p) { return __uint_as_float(p & 0xffff0000u); }

__device__ inline void gload_lds16(const void* g, void* l) {
  __builtin_amdgcn_global_load_lds((const __attribute__((address_space(1))) void*)g,
                                   (__attribute__((address_space(3))) void*)l, 16, 0, 0);
}

// ---------------- fused: feat f32->bf16 | weight prep | bucket counts ----------------
__global__ __launch_bounds__(256) void fbw_k(const float* __restrict__ f,
                                             unsigned* __restrict__ fb,
                                             const float* __restrict__ W1,
                                             const float* __restrict__ Wb,
                                             const float* __restrict__ bb,
                                             const float* __restrict__ b1,
                                             const float* __restrict__ W2,
                                             unsigned short* __restrict__ W1e,
                                             unsigned short* __restrict__ W2e,
                                             const int* __restrict__ dst,
                                             int* __restrict__ cnts_s) {
  __shared__ int bh[NB];
  if (blockIdx.x < 25000) {
    int i = blockIdx.x * 256 + threadIdx.x;
    float2 v = ((const float2*)f)[i];
    fb[i] = pk2(v.x, v.y);
  } else if (blockIdx.x < 25080) {
    int idx = (blockIdx.x - 25000) * 256 + threadIdx.x;
    if (idx < 128 * KEXT) {
      int c = idx / KEXT, k = idx - c * KEXT;
      float v1 = 0.f;
      if (k < 128) v1 = W1[c * HID + k];
      else if (k < 144) v1 = Wb[c * 16 + (k - 128)];
      else if (k == 144) v1 = bb[c];
      else if (k == 145) v1 = b1[c];
      W1e[idx] = f2bf(v1);
    }
    if (idx < 128 * 128) W2e[idx] = f2bf(W2[(idx >> 7) * HID + (idx & 127)]);
  } else {
    int blk = blockIdx.x - 25080;          // 0..P2B-1
    int b0 = blk * EPB2, e1 = min(b0 + EPB2, NE);
    for (int i = threadIdx.x; i < NB; i += 256) bh[i] = 0;
    __syncthreads();
    for (int e = b0 + threadIdx.x; e < e1; e += 256) atomicAdd(&bh[dst[e] >> BSH], 1);
    __syncthreads();
    for (int i = threadIdx.x; i < NB; i += 256) cnts_s[i * P2B + blk] = bh[i];
  }
}

// ---------------- per-bucket scans over 2048 blocks (1024 thr, 2 entries each) ----------------
__global__ __launch_bounds__(1024) void cscan_k(int* __restrict__ cnts_s,
                                                int* __restrict__ bcnt_s,
                                                int* __restrict__ bcnt_r) {
  __shared__ int s[1024];
  int b = blockIdx.x, t = threadIdx.x;
  int x0 = cnts_s[b * P2B + 2 * t];
  int x1 = cnts_s[b * P2B + 2 * t + 1];
  int xs0 = (x0 + 1) & ~1;
  int xs1 = (x1 + 1) & ~1;
  // padded (Q=2) scan
  s[t] = xs0 + xs1; __syncthreads();
  for (int off = 1; off < 1024; off <<= 1) {
    int v = (t >= off) ? s[t - off] : 0; __syncthreads();
    s[t] += v; __syncthreads();
  }
  int exclp = s[t] - (xs0 + xs1);
  cnts_s[b * P2B + 2 * t] = exclp;
  cnts_s[b * P2B + 2 * t + 1] = exclp + xs0;
  if (t == 1023) bcnt_s[b] = s[1023];
  __syncthreads();
  // real totals
  s[t] = x0 + x1; __syncthreads();
  for (int off = 1; off < 1024; off <<= 1) {
    int v = (t >= off) ? s[t - off] : 0; __syncthreads();
    s[t] += v; __syncthreads();
  }
  if (t == 1023) bcnt_r[b] = s[1023];
}

// ---------------- bucket-level scans ----------------
__global__ __launch_bounds__(256) void bscan_k(const int* __restrict__ bcnt_r,
                                               const int* __restrict__ bcnt_s,
                                               int* __restrict__ bbase_r,
                                               int* __restrict__ bbase_s,
                                               int* __restrict__ rs) {
  __shared__ int s[256];
  int t = threadIdx.x;
#pragma unroll
  for (int pass = 0; pass < 2; ++pass) {
    const int* in = (pass == 0) ? bcnt_r : bcnt_s;
    int* out = (pass == 0) ? bbase_r : bbase_s;
    int x = (t < NB) ? in[t] : 0;
    s[t] = x; __syncthreads();
    for (int off = 1; off < 256; off <<= 1) {
      int v = (t >= off) ? s[t - off] : 0; __syncthreads();
      s[t] += v; __syncthreads();
    }
    if (t < NB) out[t] = s[t] - x;
    if (t == NB - 1) out[NB] = s[t];
    __syncthreads();
  }
  if (t == 0) rs[NN] = NE;
}

// ---------------- LDS counting-sort partition (2048 blocks, Q=2 pads) ----------------
// stg u32: src[0:17) | d9[17:26) | valid[26]
__global__ __launch_bounds__(256) void part3_k(const int* __restrict__ src,
                                               const int* __restrict__ dst,
                                               const float* __restrict__ ef,
                                               const int* __restrict__ bbase_s,
                                               const int* __restrict__ cnts_s,
                                               unsigned* __restrict__ stg,
                                               float4* __restrict__ efb) {
  __shared__ int th[NB], ts[NB], cnt2[NB], st_s[NB];
  __shared__ int sscan[256];
  __shared__ unsigned spk[EPB2 + 1];
  int blk = blockIdx.x, tid = threadIdx.x;
  int b0 = blk * EPB2;
  int tc = min(EPB2, NE - b0);
  if (tc < 0) tc = 0;
  for (int i = tid; i < NB; i += 256) {
    th[i] = 0; cnt2[i] = 0;
    st_s[i] = bbase_s[i] + cnts_s[i * P2B + blk];
  }
  __syncthreads();
  // phase 0: histogram + streamed L2-warm of ef
  float sink = 0.f;
  for (int le = tid; le < tc; le += 256) {
    int e = b0 + le;
    atomicAdd(&th[dst[e] >> BSH], 1);
    const float4* efp = (const float4*)(ef + (size_t)e * 16);
    float4 a = efp[0], b4 = efp[1], c4 = efp[2], d4 = efp[3];
    sink += a.x + b4.x + c4.x + d4.x;
  }
  asm volatile("" : "+v"(sink));
  __syncthreads();
  // scan th -> ts
  sscan[tid] = (tid < NB) ? th[tid] : 0;
  __syncthreads();
  for (int off = 1; off < 256; off <<= 1) {
    int v = (tid >= off) ? sscan[tid - off] : 0;
    __syncthreads();
    sscan[tid] += v;
    __syncthreads();
  }
  if (tid < NB) ts[tid] = sscan[tid] - th[tid];
  __syncthreads();
  // slot assignment: spk = b[8] | d9[9] | le[11]
  for (int le = tid; le < tc; le += 256) {
    int d = dst[b0 + le];
    int b = d >> BSH;
    int slot = ts[b] + atomicAdd(&cnt2[b], 1);
    spk[slot] = ((unsigned)b << 20) | ((unsigned)(d & (BNODES - 1)) << 11) | (unsigned)le;
  }
  __syncthreads();
  // emit in sorted order (coalesced bucket runs); ef from L2
  for (int s2 = tid; s2 < tc; s2 += 256) {
    unsigned pk = spk[s2];
    int b = pk >> 20, d9 = (pk >> 11) & 511, le = pk & 2047;
    int e = b0 + le;
    int gs = st_s[b] + (s2 - ts[b]);
    stg[gs] = (unsigned)src[e] | ((unsigned)d9 << 17) | (1u << 26);
    const float4* efp = (const float4*)(ef + (size_t)e * 16);
    float4 a = efp[0], b4 = efp[1], c4 = efp[2], d4 = efp[3];
    float4 w0, w1;
    w0.x = __uint_as_float(pk2(a.x, a.y));   w0.y = __uint_as_float(pk2(a.z, a.w));
    w0.z = __uint_as_float(pk2(b4.x, b4.y)); w0.w = __uint_as_float(pk2(b4.z, b4.w));
    w1.x = __uint_as_float(pk2(c4.x, c4.y)); w1.y = __uint_as_float(pk2(c4.z, c4.w));
    w1.z = __uint_as_float(pk2(d4.x, d4.y)); w1.w = __uint_as_float(pk2(d4.z, d4.w));
    efb[(size_t)gs * 2] = w0;
    efb[(size_t)gs * 2 + 1] = w1;
  }
  __syncthreads();
  // pad-fill stg to Q=2
  for (int i = tid; i < NB; i += 256) {
    int c = th[i];
    if (c & 1) stg[st_s[i] + c] = 0u;
  }
}

// ---------------- node sort + per-node serial ef sum ----------------
__global__ __launch_bounds__(512) void bsort_k(const unsigned* __restrict__ stg,
                                               const int* __restrict__ bbase_s,
                                               const int* __restrict__ bbase_r,
                                               const unsigned* __restrict__ efbu,
                                               int* __restrict__ rs,
                                               unsigned* __restrict__ fin,
                                               unsigned* __restrict__ efsum) {
  __shared__ int h[BNODES], sc[BNODES], cur[BNODES];
  __shared__ int tot;
  __shared__ unsigned slds[SCAP];    // 40 KB: src[0:17) | ge_rel[17:31)
  int b = blockIdx.x, n0 = b << BSH, tid = threadIdx.x;
  int s0p = bbase_s[b], e1p = bbase_s[b + 1];
  int s0r = bbase_r[b];
  h[tid] = 0;
  __syncthreads();
  for (int i = s0p + tid; i < e1p; i += 512) {
    unsigned rec = stg[i];
    if (rec >> 26) atomicAdd(&h[(rec >> 17) & (BNODES - 1)], 1);
  }
  __syncthreads();
  sc[tid] = h[tid];
  __syncthreads();
  for (int off = 1; off < BNODES; off <<= 1) {
    int v = (tid >= off) ? sc[tid - off] : 0;
    __syncthreads();
    sc[tid] += v;
    __syncthreads();
  }
  int excl = sc[tid] - h[tid];
  cur[tid] = excl;
  int n = n0 + tid;
  if (n < NN) rs[n] = s0r + excl;
  if (tid == BNODES - 1) tot = sc[tid];
  __syncthreads();
  for (int i = s0p + tid; i < e1p; i += 512) {
    unsigned rec = stg[i];
    if (rec >> 26) {
      int d = (rec >> 17) & (BNODES - 1);
      int p = atomicAdd(&cur[d], 1);
      slds[p] = (rec & 0x1FFFF) | ((unsigned)(i - s0p) << 17);
    }
  }
  __syncthreads();
  int T = tot;
  for (int j = tid; j < T; j += 512) fin[s0r + j] = slds[j] & 0x1FFFF;
  // per-node serial ef sum over L2-resident efb window (registers, no LDS traffic)
  if (n < NN) {
    float a[16];
#pragma unroll
    for (int k = 0; k < 16; ++k) a[k] = 0.f;
    for (int j = excl; j < sc[tid]; ++j) {
      unsigned rec = slds[j];
      const unsigned* ep = efbu + ((size_t)s0p + (rec >> 17)) * 8;
#pragma unroll
      for (int k = 0; k < 8; ++k) {
        unsigned u = ep[k];
        a[2 * k] += bflo(u);
        a[2 * k + 1] += bfhi(u);
      }
    }
    unsigned* op = efsum + (size_t)n * 8;
#pragma unroll
    for (int k = 0; k < 8; ++k) op[k] = pk2(a[2 * k], a[2 * k + 1]);
  }
}

// ---------------- gather: feat mailbox (16-wide ILP, XCD swizzle) ----------------
__global__ __launch_bounds__(256) void feg_k(const unsigned* __restrict__ fb,
                                             const int* __restrict__ rs,
                                             const unsigned* __restrict__ fin,
                                             const unsigned* __restrict__ efsum,
                                             unsigned short* __restrict__ A1) {
  int bid = (int)(blockIdx.x & 7) * 3125 + (int)(blockIdx.x >> 3);
  int wid = threadIdx.x >> 6, lane = threadIdx.x & 63;
  int node = bid * 4 + wid;
  if (node >= NN) return;
  int start = rs[node], end = rs[node + 1];
  float ax0 = 0.f, ay0 = 0.f, ax1 = 0.f, ay1 = 0.f;
  float ax2 = 0.f, ay2 = 0.f, ax3 = 0.f, ay3 = 0.f;
  float ax4 = 0.f, ay4 = 0.f, ax5 = 0.f, ay5 = 0.f;
  float ax6 = 0.f, ay6 = 0.f, ax7 = 0.f, ay7 = 0.f;
  int i = start;
  // 16-wide main loop: 16 outstanding gathers per lane
  for (; i + 16 <= end; i += 16) {
    int sl = 0;
    if (lane < 16) sl = (int)fin[i + lane];
    int s0 = __shfl(sl, 0), s1 = __shfl(sl, 1), s2 = __shfl(sl, 2), s3 = __shfl(sl, 3);
    int s4 = __shfl(sl, 4), s5 = __shfl(sl, 5), s6 = __shfl(sl, 6), s7 = __shfl(sl, 7);
    int s8 = __shfl(sl, 8), s9 = __shfl(sl, 9), s10 = __shfl(sl, 10), s11 = __shfl(sl, 11);
    int s12 = __shfl(sl, 12), s13 = __shfl(sl, 13), s14 = __shfl(sl, 14), s15 = __shfl(sl, 15);
    unsigned p0 = fb[s0 * 64 + lane];
    unsigned p1 = fb[s1 * 64 + lane];
    unsigned p2 = fb[s2 * 64 + lane];
    unsigned p3 = fb[s3 * 64 + lane];
    unsigned p4 = fb[s4 * 64 + lane];
    unsigned p5 = fb[s5 * 64 + lane];
    unsigned p6 = fb[s6 * 64 + lane];
    unsigned p7 = fb[s7 * 64 + lane];
    unsigned p8 = fb[s8 * 64 + lane];
    unsigned p9 = fb[s9 * 64 + lane];
    unsigned p10 = fb[s10 * 64 + lane];
    unsigned p11 = fb[s11 * 64 + lane];
    unsigned p12 = fb[s12 * 64 + lane];
    unsigned p13 = fb[s13 * 64 + lane];
    unsigned p14 = fb[s14 * 64 + lane];
    unsigned p15 = fb[s15 * 64 + lane];
    ax0 += bflo(p0); ay0 += bfhi(p0);
    ax1 += bflo(p1); ay1 += bfhi(p1);
    ax2 += bflo(p2); ay2 += bfhi(p2);
    ax3 += bflo(p3); ay3 += bfhi(p3);
    ax4 += bflo(p4); ay4 += bfhi(p4);
    ax5 += bflo(p5); ay5 += bfhi(p5);
    ax6 += bflo(p6); ay6 += bfhi(p6);
    ax7 += bflo(p7); ay7 += bfhi(p7);
    ax0 += bflo(p8); ay0 += bfhi(p8);
    ax1 += bflo(p9); ay1 += bfhi(p9);
    ax2 += bflo(p10); ay2 += bfhi(p10);
    ax3 += bflo(p11); ay3 += bfhi(p11);
    ax4 += bflo(p12); ay4 += bfhi(p12);
    ax5 += bflo(p13); ay5 += bfhi(p13);
    ax6 += bflo(p14); ay6 += bfhi(p14);
    ax7 += bflo(p15); ay7 += bfhi(p15);
  }
  for (; i + 8 <= end; i += 8) {
    int sl = 0;
    if (lane < 8) sl = (int)fin[i + lane];
    int s0 = __shfl(sl, 0), s1 = __shfl(sl, 1), s2 = __shfl(sl, 2), s3 = __shfl(sl, 3);
    int s4 = __shfl(sl, 4), s5 = __shfl(sl, 5), s6 = __shfl(sl, 6), s7 = __shfl(sl, 7);
    unsigned p0 = fb[s0 * 64 + lane];
    unsigned p1 = fb[s1 * 64 + lane];
    unsigned p2 = fb[s2 * 64 + lane];
    unsigned p3 = fb[s3 * 64 + lane];
    unsigned p4 = fb[s4 * 64 + lane];
    unsigned p5 = fb[s5 * 64 + lane];
    unsigned p6 = fb[s6 * 64 + lane];
    unsigned p7 = fb[s7 * 64 + lane];
    ax0 += bflo(p0); ay0 += bfhi(p0);
    ax1 += bflo(p1); ay1 += bfhi(p1);
    ax2 += bflo(p2); ay2 += bfhi(p2);
    ax3 += bflo(p3); ay3 += bfhi(p3);
    ax4 += bflo(p4); ay4 += bfhi(p4);
    ax5 += bflo(p5); ay5 += bfhi(p5);
    ax6 += bflo(p6); ay6 += bfhi(p6);
    ax7 += bflo(p7); ay7 += bfhi(p7);
  }
  for (; i < end; ++i) {
    int sl = 0;
    if (lane == 0) sl = (int)fin[i];
    int s0 = __shfl(sl, 0);
    unsigned p0 = fb[s0 * 64 + lane];
    ax0 += bflo(p0); ay0 += bfhi(p0);
  }
  float ax = ((ax0 + ax1) + (ax2 + ax3)) + ((ax4 + ax5) + (ax6 + ax7));
  float ay = ((ay0 + ay1) + (ay2 + ay3)) + ((ay4 + ay5) + (ay6 + ay7));
  char* rowp = (char*)A1 + (size_t)node * ROWB;
  *(unsigned*)(rowp + lane * 4) = pk2(ax, ay);
  if (lane < 8) {
    *(unsigned*)(rowp + 256 + 4 * lane) = efsum[(size_t)node * 8 + lane];
  } else if (lane < 16) {
    int j2 = lane - 8;
    *(unsigned*)(rowp + 288 + 4 * j2) =
        (j2 == 0) ? pk2((float)(end - start), 1.0f) : 0u;
  }
}

// ---------------- GEMM 1: 128-row tile, K=160, stats -> privatized ----------------
__global__ __launch_bounds__(256) void gemm1_k(
    const unsigned short* __restrict__ A, const unsigned short* __restrict__ W,
    unsigned short* __restrict__ outb, float* __restrict__ statsP) {
  __shared__ __align__(16) char sA[128 * ROWB];
  __shared__ __align__(16) char sW[128 * ROWB];
  const int tid = threadIdx.x;
  const int wid = tid >> 6, lane = tid & 63;
  const size_t r0 = (size_t)blockIdx.x * 128;

#pragma unroll
  for (int q = 0; q < 10; ++q) {
    int s = q * 256 + tid;
    int row = (s * 3277) >> 16;
    int c = s - row * 20;
    int csrc = (c < 16) ? (c ^ (row & 7)) : (16 + ((c - 16) ^ (row & 3)));
    gload_lds16((const char*)A + (r0 + row) * ROWB + csrc * 16,
                sA + (size_t)(q * 256 + wid * 64) * 16);
  }
#pragma unroll
  for (int q = 0; q < 10; ++q) {
    int s = q * 256 + tid;
    int row = (s * 3277) >> 16;
    int c = s - row * 20;
    int csrc = (c < 16) ? (c ^ (row & 7)) : (16 + ((c - 16) ^ (row & 3)));
    gload_lds16((const char*)W + (size_t)row * ROWB + csrc * 16,
                sW + (size_t)(q * 256 + wid * 64) * 16);
  }
  __syncthreads();

  const int l15 = lane & 15;
  const int kgr = lane >> 4;
  bf16x8 afrag[2][5];
#pragma unroll
  for (int rt = 0; rt < 2; ++rt) {
    int arow = wid * 32 + rt * 16 + l15;
#pragma unroll
    for (int ks = 0; ks < 5; ++ks) {
      int creq = ks * 4 + kgr;
      int csw = (creq < 16) ? (creq ^ (arow & 7)) : (16 + ((creq - 16) ^ (arow & 3)));
      afrag[rt][ks] = *(const bf16x8*)(sA + arow * ROWB + csw * 16);
    }
  }
  f32x4 acc[2][8];
#pragma unroll
  for (int rt = 0; rt < 2; ++rt)
#pragma unroll
    for (int ct = 0; ct < 8; ++ct) acc[rt][ct] = (f32x4){0.f, 0.f, 0.f, 0.f};
#pragma unroll
  for (int ct = 0; ct < 8; ++ct) {
    int brow = ct * 16 + l15;
#pragma unroll
    for (int ks = 0; ks < 5; ++ks) {
      int creq = ks * 4 + kgr;
      int csw = (creq < 16) ? (creq ^ (brow & 7)) : (16 + ((creq - 16) ^ (brow & 3)));
      bf16x8 bfrag = *(const bf16x8*)(sW + brow * ROWB + csw * 16);
      acc[0][ct] = __builtin_amdgcn_mfma_f32_16x16x32_bf16(afrag[0][ks], bfrag, acc[0][ct], 0, 0, 0);
      acc[1][ct] = __builtin_amdgcn_mfma_f32_16x16x32_bf16(afrag[1][ks], bfrag, acc[1][ct], 0, 0, 0);
    }
  }

  float cs[8], cq[8];
#pragma unroll
  for (int ct = 0; ct < 8; ++ct) { cs[ct] = 0.f; cq[ct] = 0.f; }
#pragma unroll
  for (int rt = 0; rt < 2; ++rt) {
    const size_t orow0 = r0 + wid * 32 + rt * 16 + kgr * 4;
#pragma unroll
    for (int ct = 0; ct < 8; ++ct) {
      int col = ct * 16 + l15;
#pragma unroll
      for (int r = 0; r < 4; ++r) {
        size_t row = orow0 + r;
        if (row < NN) {
          float v = acc[rt][ct][r];
          outb[row * HID + col] = f2bf(v);
          cs[ct] += v; cq[ct] += v * v;
        }
      }
    }
  }
#pragma unroll
  for (int ct = 0; ct < 8; ++ct) {
    cs[ct] += __shfl_xor(cs[ct], 16); cs[ct] += __shfl_xor(cs[ct], 32);
    cq[ct] += __shfl_xor(cq[ct], 16); cq[ct] += __shfl_xor(cq[ct], 32);
  }
  __syncthreads();
  float* red = (float*)sA;
  if (lane < 16) {
#pragma unroll
    for (int ct = 0; ct < 8; ++ct) {
      red[wid * 256 + ct * 16 + l15] = cs[ct];
      red[wid * 256 + 128 + ct * 16 + l15] = cq[ct];
    }
  }
  __syncthreads();
  if (tid < 256) {
    float* base = statsP + (size_t)(blockIdx.x & 15) * 512;
    float s_ = red[tid] + red[256 + tid] + red[512 + tid] + red[768 + tid];
    atomicAdd(&base[tid], s_);
  }
}

// ---------------- stats reduce ----------------
__global__ void bnred_k(const float* __restrict__ statsP, int base,
                        const float* __restrict__ gamma, const float* __restrict__ beta,
                        float* __restrict__ scale, float* __restrict__ shift) {
  int c = threadIdx.x;
  if (c < 128) {
    float s_ = 0.f, q_ = 0.f;
#pragma unroll
    for (int i = 0; i < 16; ++i) {
      s_ += statsP[i * 512 + base + c];
      q_ += statsP[i * 512 + base + 128 + c];
    }
    const float invN = 1.f / (float)NN;
    float m = s_ * invN;
    float var = q_ * invN - m * m;
    float inv = rsqrtf(var + BN_EPS);
    float sc = gamma[c] * inv;
    scale[c] = sc;
    shift[c] = beta[c] - m * sc;
  }
}

// ---------------- GEMM 2: fused BN1+ReLU A-stage, bf16 residual, in-place ----------------
__global__ __launch_bounds__(256) void gemm2_k(
    const unsigned* __restrict__ t, const unsigned short* __restrict__ W,
    const float* __restrict__ scale, const float* __restrict__ shift,
    const float* __restrict__ b2, const unsigned* __restrict__ fbres,
    unsigned short* __restrict__ outb, float* __restrict__ statsP) {
  __shared__ __align__(16) char sA[128 * 256];
  __shared__ __align__(16) char sW[128 * 256];
  __shared__ float ssc[128], ssh[128];
  const int tid = threadIdx.x;
  const int wid = tid >> 6, lane = tid & 63;
  const size_t r0 = (size_t)blockIdx.x * 128;

  if (tid < 128) {
    ssc[tid] = scale[tid];
    ssh[tid] = shift[tid];
  }
#pragma unroll
  for (int q = 0; q < 8; ++q) {
    int s = q * 256 + tid;
    int row = s >> 4, c = s & 15;
    int csrc = c ^ (row & 7);
    gload_lds16((const char*)W + (size_t)row * 256 + csrc * 16,
                sW + (size_t)(q * 256 + wid * 64) * 16);
  }
  __syncthreads();

#pragma unroll
  for (int q = 0; q < 8; ++q) {
    int s = q * 256 + tid;
    int sr = s >> 4, c = s & 15;
    size_t grow = r0 + sr;
    uint4 v = make_uint4(0, 0, 0, 0);
    if (grow < NN) v = *(const uint4*)(t + grow * 64 + c * 4);
    int k = c * 8;
    unsigned o0 = pk2(fmaxf(0.f, fmaf(bflo(v.x), ssc[k + 0], ssh[k + 0])),
                      fmaxf(0.f, fmaf(bfhi(v.x), ssc[k + 1], ssh[k + 1])));
    unsigned o1 = pk2(fmaxf(0.f, fmaf(bflo(v.y), ssc[k + 2], ssh[k + 2])),
                      fmaxf(0.f, fmaf(bfhi(v.y), ssc[k + 3], ssh[k + 3])));
    unsigned o2 = pk2(fmaxf(0.f, fmaf(bflo(v.z), ssc[k + 4], ssh[k + 4])),
                      fmaxf(0.f, fmaf(bfhi(v.z), ssc[k + 5], ssh[k + 5])));
    unsigned o3 = pk2(fmaxf(0.f, fmaf(bflo(v.w), ssc[k + 6], ssh[k + 6])),
                      fmaxf(0.f, fmaf(bfhi(v.w), ssc[k + 7], ssh[k + 7])));
    int csw = c ^ (sr & 7);
    uint4 w4; w4.x = o0; w4.y = o1; w4.z = o2; w4.w = o3;
    *(uint4*)(sA + sr * 256 + csw * 16) = w4;
  }
  __syncthreads();

  const int l15 = lane & 15;
  const int kgr = lane >> 4;
  bf16x8 afrag[2][4];
#pragma unroll
  for (int rt = 0; rt < 2; ++rt) {
    int arow = wid * 32 + rt * 16 + l15;
#pragma unroll
    for (int ks = 0; ks < 4; ++ks) {
      int creq = ks * 4 + kgr;
      int csw = creq ^ (arow & 7);
      afrag[rt][ks] = *(const bf16x8*)(sA + arow * 256 + csw * 16);
    }
  }
  f32x4 acc[2][8];
#pragma unroll
  for (int rt = 0; rt < 2; ++rt)
#pragma unroll
    for (int ct = 0; ct < 8; ++ct) acc[rt][ct] = (f32x4){0.f, 0.f, 0.f, 0.f};
#pragma unroll
  for (int ct = 0; ct < 8; ++ct) {
    int brow = ct * 16 + l15;
#pragma unroll
    for (int ks = 0; ks < 4; ++ks) {
      int creq = ks * 4 + kgr;
      int csw = creq ^ (brow & 7);
      bf16x8 bfrag = *(const bf16x8*)(sW + brow * 256 + csw * 16);
      acc[0][ct] = __builtin_amdgcn_mfma_f32_16x16x32_bf16(afrag[0][ks], bfrag, acc[0][ct], 0, 0, 0);
      acc[1][ct] = __builtin_amdgcn_mfma_f32_16x16x32_bf16(afrag[1][ks], bfrag, acc[1][ct], 0, 0, 0);
    }
  }

  float cs[8], cq[8];
#pragma unroll
  for (int ct = 0; ct < 8; ++ct) { cs[ct] = 0.f; cq[ct] = 0.f; }
#pragma unroll
  for (int rt = 0; rt < 2; ++rt) {
    const size_t orow0 = r0 + wid * 32 + rt * 16 + kgr * 4;
#pragma unroll
    for (int ct = 0; ct < 8; ++ct) {
      int col = ct * 16 + l15;
      float b2v = b2[col];
      int ci = col >> 1, par = col & 1;
#pragma unroll
      for (int r = 0; r < 4; ++r) {
        size_t row = orow0 + r;
        if (row < NN) {
          unsigned u = fbres[row * 64 + ci];
          float resid = par ? bfhi(u) : bflo(u);
          float v = acc[rt][ct][r] + b2v + resid;
          outb[row * HID + col] = f2bf(v);
          cs[ct] += v; cq[ct] += v * v;
        }
      }
    }
  }
#pragma unroll
  for (int ct = 0; ct < 8; ++ct) {
    cs[ct] += __shfl_xor(cs[ct], 16); cs[ct] += __shfl_xor(cs[ct], 32);
    cq[ct] += __shfl_xor(cq[ct], 16); cq[ct] += __shfl_xor(cq[ct], 32);
  }
  __syncthreads();
  float* red = (float*)sA;
  if (lane < 16) {
#pragma unroll
    for (int ct = 0; ct < 8; ++ct) {
      red[wid * 256 + ct * 16 + l15] = cs[ct];
      red[wid * 256 + 128 + ct * 16 + l15] = cq[ct];
    }
  }
  __syncthreads();
  if (tid < 256) {
    float* base = statsP + (size_t)(blockIdx.x & 15) * 512 + 256;
    float s_ = red[tid] + red[256 + tid] + red[512 + tid] + red[768 + tid];
    atomicAdd(&base[tid], s_);
  }
}

// ---------------- final BN+ReLU -> f32 out ----------------
__global__ __launch_bounds__(256) void bn_final_k(const unsigned* __restrict__ t,
                                                  const float* __restrict__ scale,
                                                  const float* __restrict__ shift,
                                                  float* __restrict__ o) {
  __shared__ float ssc[128], ssh[128];
  int tid = threadIdx.x;
  if (tid < 128) { ssc[tid] = scale[tid]; ssh[tid] = shift[tid]; }
  __syncthreads();
  int i = blockIdx.x * 256 + tid;
  if (i >= NN * 64) return;
  unsigned p = t[i];
  int c = (i & 63) * 2;
  float2 v;
  v.x = fmaxf(0.f, fmaf(bflo(p), ssc[c], ssh[c]));
  v.y = fmaxf(0.f, fmaf(bfhi(p), ssc[c + 1], ssh[c + 1]));
  ((float2*)o)[i] = v;
}

extern "C" void kernel_launch(void* const* d_in, const int* in_sizes, int n_in,
                              void* d_out, int out_size, void* d_ws, size_t ws_size,
                              hipStream_t stream) {
  (void)in_sizes; (void)n_in; (void)out_size; (void)ws_size;
  const float* features   = (const float*)d_in[0];
  const float* edge_feats = (const float*)d_in[1];
  const int*   src        = (const int*)d_in[2];
  const int*   dst        = (const int*)d_in[3];
  const float* Wb         = (const float*)d_in[4];
  const float* bb         = (const float*)d_in[5];
  const float* W1         = (const float*)d_in[6];
  const float* b1         = (const float*)d_in[7];
  const float* W2         = (const float*)d_in[8];
  const float* b2         = (const float*)d_in[9];
  const float* gamma1     = (const float*)d_in[10];
  const float* beta1      = (const float*)d_in[11];
  const float* gamma2     = (const float*)d_in[12];
  const float* beta2      = (const float*)d_in[13];
  float* outp = (float*)d_out;

  char* wsb = (char*)d_ws;
  size_t off = 0;
  auto alloc = [&](size_t nbytes) -> void* {
    off = (off + 255) & ~(size_t)255;
    void* p = wsb + off;
    off += nbytes;
    return p;
  };
  const size_t STGN = (size_t)NE + (size_t)NB * P2B + 64;   // Q=2 padding
  int* row_start = (int*)alloc((size_t)(NN + 1) * 4);
  int* bcnt_r    = (int*)alloc(NB * 4);
  int* bcnt_s    = (int*)alloc(NB * 4);
  int* bbase_r   = (int*)alloc((NB + 1) * 4);
  int* bbase_s   = (int*)alloc((NB + 1) * 4);
  int* cnts_s    = (int*)alloc((size_t)NB * P2B * 4);
  float* statsP  = (float*)alloc(16 * 512 * 4);
  float* scsh    = (float*)alloc(512 * 4);
  unsigned* featb = (unsigned*)alloc((size_t)NN * 64 * 4);          // fb, stays live
  unsigned short* tbuf = (unsigned short*)alloc((size_t)NROWP * HID * 2);
  unsigned short* A1e = (unsigned short*)alloc((size_t)NROWP * ROWB);
  unsigned short* W1e = (unsigned short*)alloc(128 * KEXT * 2);
  unsigned short* W2e = (unsigned short*)alloc(128 * 128 * 2);
  unsigned* stg  = (unsigned*)alloc(STGN * 4);
  unsigned* fin  = (unsigned*)alloc((size_t)NE * 4);
  float4* efb    = (float4*)alloc(STGN * 32);
  unsigned* efsum = (unsigned*)alloc((size_t)NN * 32);

  hipMemsetAsync(statsP, 0, 16 * 512 * 4, stream);
  hipMemsetAsync((char*)A1e + (size_t)NN * ROWB, 0, (NROWP - NN) * ROWB, stream);

  fbw_k<<<25080 + P2B, 256, 0, stream>>>(features, featb, W1, Wb, bb, b1, W2,
                                         W1e, W2e, dst, cnts_s);
  cscan_k<<<NB, 1024, 0, stream>>>(cnts_s, bcnt_s, bcnt_r);
  bscan_k<<<1, 256, 0, stream>>>(bcnt_r, bcnt_s, bbase_r, bbase_s, row_start);
  part3_k<<<P2B, 256, 0, stream>>>(src, dst, edge_feats, bbase_s, cnts_s, stg, efb);
  bsort_k<<<NB, 512, 0, stream>>>(stg, bbase_s, bbase_r, (const unsigned*)efb,
                                  row_start, fin, efsum);
  feg_k<<<25000, 256, 0, stream>>>(featb, row_start, fin, efsum, A1e);

  gemm1_k<<<GGRID, 256, 0, stream>>>(A1e, W1e, tbuf, statsP);
  bnred_k<<<1, 128, 0, stream>>>(statsP, 0, gamma1, beta1, scsh, scsh + 128);
  gemm2_k<<<GGRID, 256, 0, stream>>>((const unsigned*)tbuf, W2e, scsh, scsh + 128,
                                     b2, featb, tbuf, statsP);
  bnred_k<<<1, 128, 0, stream>>>(statsP, 256, gamma2, beta2, scsh + 256, scsh + 384);
  bn_final_k<<<25000, 256, 0, stream>>>((const unsigned*)tbuf, scsh + 256, scsh + 384,
                                        outp);
}